// Round 1
// baseline (566.714 us; speedup 1.0000x reference)
//
#include <hip/hip_runtime.h>
#include <hip/hip_bf16.h>

// DCN layer, fused:
//   s[i]     = sum_j x_l[i,j] * w[j]
//   out[i,j] = x_0[i,j] * s[i] + b[j] + x_l[i,j]
// Shapes: x_l, x_0: [B=65536, DIM=1024] fp32; w, b: [1024] fp32; out: [B, DIM] fp32.
// Memory-bound: 768 MB ideal traffic -> ~122 us at 6.3 TB/s.

#define DIM 1024
#define BLOCK 256   // 4 waves; each thread owns 4 contiguous floats (float4)

__global__ __launch_bounds__(BLOCK) void dcn_fused_kernel(
    const float* __restrict__ x_l,
    const float* __restrict__ x_0,
    const float* __restrict__ w,
    const float* __restrict__ b,
    float* __restrict__ out)
{
    const int row = blockIdx.x;
    const int tid = threadIdx.x;                 // 0..255
    const size_t base = (size_t)row * DIM + (size_t)tid * 4;
    const int col = tid * 4;

    // x_l stays in registers: HBM reads it exactly once.
    const float4 xl = *(const float4*)(x_l + base);
    const float4 wv = *(const float4*)(w + col);   // 4 KB total, L1/L2 resident

    float partial = xl.x * wv.x + xl.y * wv.y + xl.z * wv.z + xl.w * wv.w;

    // Wave-64 shuffle reduction.
    #pragma unroll
    for (int off = 32; off > 0; off >>= 1)
        partial += __shfl_down(partial, off, 64);

    __shared__ float wsum[4];
    const int wave = tid >> 6;
    const int lane = tid & 63;
    if (lane == 0) wsum[wave] = partial;
    __syncthreads();
    const float s = wsum[0] + wsum[1] + wsum[2] + wsum[3];

    const float4 x0 = *(const float4*)(x_0 + base);
    const float4 bv = *(const float4*)(b + col);   // 4 KB, cached

    float4 o;
    o.x = fmaf(x0.x, s, bv.x + xl.x);
    o.y = fmaf(x0.y, s, bv.y + xl.y);
    o.z = fmaf(x0.z, s, bv.z + xl.z);
    o.w = fmaf(x0.w, s, bv.w + xl.w);

    *(float4*)(out + base) = o;
}

extern "C" void kernel_launch(void* const* d_in, const int* in_sizes, int n_in,
                              void* d_out, int out_size, void* d_ws, size_t ws_size,
                              hipStream_t stream) {
    const float* x_l = (const float*)d_in[0];
    const float* x_0 = (const float*)d_in[1];
    const float* w   = (const float*)d_in[2];
    const float* b   = (const float*)d_in[3];
    float* out = (float*)d_out;

    const int B = in_sizes[0] / DIM;   // 65536
    dcn_fused_kernel<<<B, BLOCK, 0, stream>>>(x_l, x_0, w, b, out);
}